// Round 4
// baseline (849.992 us; speedup 1.0000x reference)
//
#include <hip/hip_runtime.h>
#include <math.h>

#define N_NODES 100000
#define N_EDGES 3200000
#define F_IN    512
#define HID     16

// ---- binning geometry ----
#define NBKT     196            // buckets of 512 nodes (100000 >> 9 -> max 195)
#define BKT_NODES 512
#define BKT_CAP  18000          // avg 16327, sigma 128 -> 13 sigma margin
#define BIN_BLOCKS 512
#define CHUNK_E  1024
#define NCHUNKS  (N_EDGES / CHUNK_E)   // 3125 exactly

// ---- gemm1 geometry ----
#define ROWS_PER_CHUNK 8
#define NCHUNK (N_NODES / ROWS_PER_CHUNK)   // 12500 exactly
#define GEMM1_BLOCKS 512

typedef const __attribute__((address_space(1))) void g_void;
typedef __attribute__((address_space(3))) void l_void;

// ---------------------------------------------------------------------------
// Binning pass: pack (src, dst&511) into 4B word, append to bucket dst>>9.
// Block-staged LDS buffers -> coalesced bucket appends (L2 merges partial
// lines since each bucket region fills front-to-back). Also counts deg.
__global__ __launch_bounds__(256)
void k_bin(const int* __restrict__ src, const int* __restrict__ dst,
           int* __restrict__ deg, int* __restrict__ gcur,
           unsigned* __restrict__ bins) {
    __shared__ unsigned stage[NBKT][64];
    __shared__ int cnt[NBKT];
    __shared__ int gb[NBKT];
    const int tid = threadIdx.x;

    for (int c = blockIdx.x; c < NCHUNKS; c += BIN_BLOCKS) {
        for (int b = tid; b < NBKT; b += 256) cnt[b] = 0;
        __syncthreads();
        const int base = c * CHUNK_E;
#pragma unroll
        for (int j = 0; j < 4; ++j) {
            int e = base + j * 256 + tid;
            int d = dst[e];
            int s = src[e];
            atomicAdd(&deg[d], 1);
            int b = d >> 9;
            unsigned w = (unsigned)s | ((unsigned)(d & 511) << 17);
            int p = atomicAdd(&cnt[b], 1);
            if (p < 64) {
                stage[b][p] = w;
            } else {  // statistically ~never (cap = 11 sigma); correct anyway
                int g = atomicAdd(&gcur[b], 1);
                bins[(size_t)b * BKT_CAP + g] = w;
            }
        }
        __syncthreads();
        if (tid < NBKT) {                 // parallel cursor reservation
            int n = cnt[tid]; if (n > 64) n = 64;
            cnt[tid] = n;
            gb[tid] = atomicAdd(&gcur[tid], n);
        }
        __syncthreads();
        const int grp = tid >> 4, ln = tid & 15;
        for (int b = grp; b < NBKT; b += 16) {   // 16-lane coalesced copies
            int n = cnt[b], g0 = gb[b];
            for (int j = ln; j < n; j += 16)
                bins[(size_t)b * BKT_CAP + g0 + j] = stage[b][j];
        }
        __syncthreads();
    }
}

__global__ void k_dinv(const int* __restrict__ deg, float* __restrict__ dinv) {
    int i = blockIdx.x * blockDim.x + threadIdx.x;
    if (i < N_NODES) dinv[i] = rsqrtf((float)deg[i] + 1.0f);  // +1 = self-loop
}

// ---------------------------------------------------------------------------
// GEMM1: hs1[i][k] = (sum_f x[i][f] * W1[f][k]) * dinv[i]
// 2-phase global_load_lds pipeline, counted vmcnt(4) + raw s_barrier.
__global__ __launch_bounds__(256, 2)
void k_gemm1(const float* __restrict__ x, const float* __restrict__ W1,
             const float* __restrict__ dinv, float* __restrict__ hs1) {
    __shared__ float xs[2 * ROWS_PER_CHUNK * F_IN];   // 2 x 16KB
    const int tid  = threadIdx.x;
    const int lane = tid & 63;
    const int wib  = tid >> 6;
    const int q    = lane >> 4;
    const int k    = lane & 15;

    float w[128];
    {
        const float* wp = W1 + (size_t)(q * 128) * HID + k;
#pragma unroll
        for (int j = 0; j < 128; ++j) w[j] = wp[(size_t)j * HID];
    }

    int chunk = blockIdx.x;
    int par = 0;
    {
        const float* gb = x + (size_t)chunk * (ROWS_PER_CHUNK * F_IN);
#pragma unroll
        for (int j = 0; j < 4; ++j) {
            int cidx = j * 4 + wib;
            __builtin_amdgcn_global_load_lds(
                (g_void*)(gb + cidx * 256 + lane * 4),
                (l_void*)(xs + cidx * 256), 16, 0, 0);
        }
    }

    for (; chunk < NCHUNK; chunk += GEMM1_BLOCKS) {
        const int nxt = chunk + GEMM1_BLOCKS;
        if (nxt < NCHUNK) {
            const float* gb = x + (size_t)nxt * (ROWS_PER_CHUNK * F_IN);
            float* lb = xs + (par ^ 1) * (ROWS_PER_CHUNK * F_IN);
#pragma unroll
            for (int j = 0; j < 4; ++j) {
                int cidx = j * 4 + wib;
                __builtin_amdgcn_global_load_lds(
                    (g_void*)(gb + cidx * 256 + lane * 4),
                    (l_void*)(lb + cidx * 256), 16, 0, 0);
            }
            asm volatile("s_waitcnt vmcnt(4)" ::: "memory");
        } else {
            asm volatile("s_waitcnt vmcnt(0)" ::: "memory");
        }
        __builtin_amdgcn_sched_barrier(0);
        __builtin_amdgcn_s_barrier();
        __builtin_amdgcn_sched_barrier(0);

        const float* xr0 = xs + par * (ROWS_PER_CHUNK * F_IN) + (wib * 2) * F_IN + q * 128;
        const float* xr1 = xr0 + F_IN;
        float a0 = 0.f, c0 = 0.f, a1 = 0.f, c1 = 0.f;
#pragma unroll
        for (int c = 0; c < 32; ++c) {
            float4 v0 = ((const float4*)xr0)[c];
            float4 v1 = ((const float4*)xr1)[c];
            a0 = fmaf(v0.x, w[4 * c + 0], a0);
            c0 = fmaf(v0.y, w[4 * c + 1], c0);
            a0 = fmaf(v0.z, w[4 * c + 2], a0);
            c0 = fmaf(v0.w, w[4 * c + 3], c0);
            a1 = fmaf(v1.x, w[4 * c + 0], a1);
            c1 = fmaf(v1.y, w[4 * c + 1], c1);
            a1 = fmaf(v1.z, w[4 * c + 2], a1);
            c1 = fmaf(v1.w, w[4 * c + 3], c1);
        }
        float s0 = a0 + c0, s1 = a1 + c1;
        s0 += __shfl_xor(s0, 16);
        s0 += __shfl_xor(s0, 32);
        s1 += __shfl_xor(s1, 16);
        s1 += __shfl_xor(s1, 32);
        const int row = chunk * ROWS_PER_CHUNK + wib * 2;
        if (q == 0) {
            hs1[(size_t)row * HID + k]       = s0 * dinv[row];
            hs1[(size_t)(row + 1) * HID + k] = s1 * dinv[row + 1];
        }
        __builtin_amdgcn_sched_barrier(0);
        __builtin_amdgcn_s_barrier();
        __builtin_amdgcn_sched_barrier(0);
        par ^= 1;
    }
}

// ---------------------------------------------------------------------------
// Layer-1 aggregation: 2 blocks per bucket (split edge range), LDS f32
// accumulator (512 nodes x 16), nonzero-only global atomic merge into hsum.
__global__ __launch_bounds__(256)
void k_agg1(const unsigned* __restrict__ bins, const int* __restrict__ gcur,
            const float* __restrict__ hs1, float* __restrict__ hsum) {
    __shared__ float acc[BKT_NODES * HID];   // 32 KB
    const int b    = blockIdx.x >> 1;
    const int half = blockIdx.x & 1;
    const int tid  = threadIdx.x;
    for (int j = tid; j < BKT_NODES * HID; j += 256) acc[j] = 0.f;
    __syncthreads();

    const int n   = gcur[b];
    const int beg = half ? (n >> 1) : 0;
    const int end = half ? n : (n >> 1);
    const unsigned* wp = bins + (size_t)b * BKT_CAP;
    const int g = tid >> 4, k = tid & 15;
#pragma unroll 8
    for (int i = beg + g; i < end; i += 16) {
        unsigned w = wp[i];                        // 16 lanes broadcast-read
        int s  = w & 0x1FFFF;
        int dl = w >> 17;
        float v = hs1[(size_t)s * HID + k];        // one 64B line per edge
        atomicAdd(&acc[dl * HID + k], v);          // ds_add_f32
    }
    __syncthreads();
    float* hb = hsum + (size_t)b * (BKT_NODES * HID);
    for (int j = tid; j < BKT_NODES * HID; j += 256) {
        float v = acc[j];
        if (v != 0.f) atomicAdd(&hb[j], v);
    }
}

// ---------------------------------------------------------------------------
// Per-node middle: z = relu((hsum+hs1)*dinv + b1); ts = (z @ W2) * dinv.
__global__ void k_mid(const float* __restrict__ hsum, const float* __restrict__ hs1,
                      const float* __restrict__ dinv, const float* __restrict__ b1,
                      const float* __restrict__ W2, float* __restrict__ ts) {
    int i = blockIdx.x * blockDim.x + threadIdx.x;
    if (i >= N_NODES) return;
    float di = dinv[i];
    const float4* A = (const float4*)(hsum + (size_t)i * HID);
    const float4* H = (const float4*)(hs1  + (size_t)i * HID);
    float t = 0.f;
#pragma unroll
    for (int c = 0; c < 4; ++c) {
        float4 a = A[c];
        float4 h = H[c];
        float z0 = fmaxf((a.x + h.x) * di + b1[4 * c + 0], 0.f);
        float z1 = fmaxf((a.y + h.y) * di + b1[4 * c + 1], 0.f);
        float z2 = fmaxf((a.z + h.z) * di + b1[4 * c + 2], 0.f);
        float z3 = fmaxf((a.w + h.w) * di + b1[4 * c + 3], 0.f);
        t += z0 * W2[4 * c + 0] + z1 * W2[4 * c + 1] + z2 * W2[4 * c + 2] + z3 * W2[4 * c + 3];
    }
    ts[i] = t * di;
}

// ---------------------------------------------------------------------------
// Layer-2 aggregation + sigmoid: one block per bucket, 2KB LDS accumulator,
// ts gathers are L2-resident (400KB table).
__global__ __launch_bounds__(256)
void k_agg2fin(const unsigned* __restrict__ bins, const int* __restrict__ gcur,
               const float* __restrict__ ts, const float* __restrict__ dinv,
               const float* __restrict__ b2, float* __restrict__ out) {
    __shared__ float acc[BKT_NODES];
    const int b = blockIdx.x, tid = threadIdx.x;
    for (int j = tid; j < BKT_NODES; j += 256) acc[j] = 0.f;
    __syncthreads();
    const int n = gcur[b];
    const unsigned* wp = bins + (size_t)b * BKT_CAP;
#pragma unroll 8
    for (int i = tid; i < n; i += 256) {
        unsigned w = wp[i];
        atomicAdd(&acc[w >> 17], ts[w & 0x1FFFF]);
    }
    __syncthreads();
    for (int l = tid; l < BKT_NODES; l += 256) {
        int nd = b * BKT_NODES + l;
        if (nd < N_NODES) {
            float z = (ts[nd] + acc[l]) * dinv[nd] + b2[0];
            out[nd] = 1.0f / (1.0f + expf(-z));
        }
    }
}

// ---------------------------------------------------------------------------
extern "C" void kernel_launch(void* const* d_in, const int* in_sizes, int n_in,
                              void* d_out, int out_size, void* d_ws, size_t ws_size,
                              hipStream_t stream) {
    const float* x  = (const float*)d_in[0];
    const float* W1 = (const float*)d_in[1];
    const float* b1 = (const float*)d_in[2];
    const float* W2 = (const float*)d_in[3];
    const float* b2 = (const float*)d_in[4];
    const int*   ei = (const int*)d_in[5];
    const int* src = ei;             // edge_index[0]
    const int* dst = ei + N_EDGES;   // edge_index[1]
    float* out = (float*)d_out;

    char* ws = (char*)d_ws;
    float*    hs1  = (float*)ws;                                   // N*HID
    float*    hsum = hs1 + (size_t)N_NODES * HID;                  // NBKT*512*16 (padded)
    int*      deg  = (int*)(hsum + (size_t)NBKT * BKT_NODES * HID);// N
    int*      gcur = deg + N_NODES;                                // NBKT (pad 256)
    float*    dinv = (float*)(gcur + 256);                         // N
    float*    ts   = dinv + N_NODES;                               // N
    unsigned* bins = (unsigned*)(ts + N_NODES);                    // NBKT*BKT_CAP

    // zero deg+gcur (adjacent) and hsum
    hipMemsetAsync(deg, 0, (N_NODES + 256) * sizeof(int), stream);
    hipMemsetAsync(hsum, 0, (size_t)NBKT * BKT_NODES * HID * sizeof(float), stream);

    k_bin    <<<BIN_BLOCKS, 256, 0, stream>>>(src, dst, deg, gcur, bins);
    k_dinv   <<<(N_NODES + 255) / 256, 256, 0, stream>>>(deg, dinv);
    k_gemm1  <<<GEMM1_BLOCKS, 256, 0, stream>>>(x, W1, dinv, hs1);
    k_agg1   <<<NBKT * 2, 256, 0, stream>>>(bins, gcur, hs1, hsum);
    k_mid    <<<(N_NODES + 255) / 256, 256, 0, stream>>>(hsum, hs1, dinv, b1, W2, ts);
    k_agg2fin<<<NBKT, 256, 0, stream>>>(bins, gcur, ts, dinv, b2, out);
}